// Round 1
// baseline (768.254 us; speedup 1.0000x reference)
//
#include <hip/hip_runtime.h>
#include <hip/hip_bf16.h>

// GraphConvNormRelu: y = einsum('bctu,puv,poc->botv', x, A*g, W) + sum_p b;
// train-mode BN over (B,T,V); relu; +x residual.  B=32, C=64, T=512, V=54, P=4.
//
// R3 structure (u-first contraction — kills the transpose kernel):
//   k_prep  : bf16 W2 [o][p*64+c], bf16 Ae [pv=p*56+v][u(64)] zero-padded,
//             bias sums, zero stat buffers.
//   k_pass1 : per block (b, 4 t):
//             step 1: Z[c][pv] = X[c][u] @ Ae[pv][u]^T — A-frags straight from
//                     global fp32 x (u-contiguous!), cvt to bf16 in regs,
//                     Ae B-frags via L1. Scatter Z -> Zt[v][p*64+c] in LDS.
//             step 2: D[v][o] = Zt[v][K=256] @ W2[o][K]^T — W2 B-frags
//                     persistent in registers. Epilogue (stores + stats)
//                     identical to the verified R2 kernel.
//             Single-buffered Zt = 33.8 KB -> 4 blocks/CU (vs 2 before).
//             x loads for t+1 prefetched during step 1 of t.
//   k_finalize, k_pass2 (unchanged).

typedef __bf16 bf16_t;
typedef __bf16 bf16x8 __attribute__((ext_vector_type(8)));
typedef __bf16 bf16x4 __attribute__((ext_vector_type(4)));
typedef float  f32x4  __attribute__((ext_vector_type(4)));
typedef unsigned int uint32;

static __device__ __forceinline__ f32x4 mfma16(bf16x8 a, bf16x8 b, f32x4 c) {
  return __builtin_amdgcn_mfma_f32_16x16x32_bf16(a, b, c, 0, 0, 0);
}
static __device__ __forceinline__ uint32 pk2(float a, float b) {
  union { __bf16 h; unsigned short u; } ua, ub;
  ua.h = (__bf16)a; ub.h = (__bf16)b;
  return (uint32)ua.u | ((uint32)ub.u << 16);
}
static __device__ __forceinline__ bf16x8 cvt8(float2 a, float2 b, float2 c, float2 d) {
  union { uint32 u[4]; bf16x8 v; } r;
  r.u[0] = pk2(a.x, a.y); r.u[1] = pk2(b.x, b.y);
  r.u[2] = pk2(c.x, c.y); r.u[3] = pk2(d.x, d.y);
  return r.v;
}

#define XTOT 56623104ull   // 32*64*512*54 floats

// Load 16 u-values (2 MFMA K-frags worth) for one c-row: u0 = quad*8 (+0..7)
// and 32+quad*8 (+0..7). The second half can run past the x buffer only in
// the final (b,c,t) corner, where every affected u is >= 54 and multiplied by
// a zero row of Ae — clamp per-float2 keeps the access in-bounds.
static __device__ __forceinline__ void loadx(float2* pf, const float* __restrict__ x,
                                             size_t xr) {
  pf[0] = *(const float2*)(x + xr);
  pf[1] = *(const float2*)(x + xr + 2);
  pf[2] = *(const float2*)(x + xr + 4);
  pf[3] = *(const float2*)(x + xr + 6);
  const size_t LIM = XTOT - 2;
  size_t o0 = xr + 32, o1 = xr + 34, o2 = xr + 36, o3 = xr + 38;
  if (o0 > LIM) o0 = LIM;
  if (o1 > LIM) o1 = LIM;
  if (o2 > LIM) o2 = LIM;
  if (o3 > LIM) o3 = LIM;
  pf[4] = *(const float2*)(x + o0);
  pf[5] = *(const float2*)(x + o1);
  pf[6] = *(const float2*)(x + o2);
  pf[7] = *(const float2*)(x + o3);
}

// ---------------- k_prep ----------------
__global__ __launch_bounds__(256) void k_prep(
    const float* __restrict__ A, const float* __restrict__ g,
    const float* __restrict__ W, const float* __restrict__ bias,
    bf16_t* __restrict__ W2, bf16_t* __restrict__ Ae,
    float* __restrict__ bsum, float* __restrict__ stats) {
  int i = blockIdx.x * 256 + threadIdx.x;
  if (i < 16384) {                       // W2[o][p*64+c] = W[p][o][c]
    int o = i >> 8, k = i & 255, p = k >> 6, c = k & 63;
    W2[i] = (bf16_t)W[p * 4096 + o * 64 + c];
  }
  if (i < 224 * 64) {                    // Ae[p*56+v][u] = A[p][u][v]*g[p][u][v]
    int pv = i >> 6, u = i & 63;
    int p = pv / 56, v = pv - p * 56;
    float val = 0.f;
    if (v < 54 && u < 54) {
      int idx = (p * 54 + u) * 54 + v;
      val = A[idx] * g[idx];
    }
    Ae[i] = (bf16_t)val;
  }
  if (i < 64) {
    float s = 0.f;
    for (int p = 0; p < 4; ++p) s += bias[p * 64 + i];
    bsum[i] = s;
  }
  if (i < 8192) stats[i] = 0.f;
}

// ---------------- k_pass1 ----------------
#define ZS 264   // Zt row stride in bf16: 132 dwords, gcd(132,32)=4 -> <=2-way banks

template<bool YBF16>
__global__ __launch_bounds__(256, 4) void k_pass1(
    const float* __restrict__ x, const bf16_t* __restrict__ W2,
    const bf16_t* __restrict__ Ae, const float* __restrict__ bsum,
    void* __restrict__ yprev, float* __restrict__ stats) {
  __shared__ bf16_t Zt[64 * ZS];   // 33792 B, single-buffered -> 4 blocks/CU

  const int tid  = threadIdx.x;
  const int bid  = blockIdx.x;
  const int b    = bid >> 7;
  const int t0   = (bid & 127) << 2;
  const int w    = tid >> 6;
  const int L    = tid & 63;
  const int quad = L >> 4;
  const int l15  = L & 15;

  // zero rows 56..63 once (step-2 A-frag pad rows; rows 54/55 get written
  // zeros every t via the zero Ae columns)
  for (int i = tid; i < 8 * ZS / 2; i += 256)
    ((uint32*)(Zt + 56 * ZS))[i] = 0u;

  // persistent step-2 B-frags: W2 row o = w*16+l15, k = kk*32+quad*8
  bf16x8 wf[8];
  #pragma unroll
  for (int kk = 0; kk < 8; ++kk)
    wf[kk] = *(const bf16x8*)(W2 + (((w << 4) + l15) << 8) + (kk << 5) + (quad << 3));

  // step-1 scatter offsets: col pv = n*16+l15 -> Zt[v][p*64 + c0], c0 = w*16+quad*4
  int zoff[14];
  #pragma unroll
  for (int n = 0; n < 14; ++n) {
    int pv = (n << 4) + l15;
    int p = pv / 56;
    int v = pv - p * 56;
    zoff[n] = v * ZS + (p << 6) + (w << 4) + (quad << 2);
  }

  const int oc  = (w << 4) + l15;      // step-2 output channel; also x c-row
  const float bsv = bsum[oc];
  float ssum = 0.f, ssq = 0.f;

  const size_t xrow0 = (size_t)((b << 6) + oc) * 27648 + (quad << 3);

  float2 pf[8];
  loadx(pf, x, xrow0 + (size_t)t0 * 54);

  for (int tt = 0; tt < 4; ++tt) {
    const int t = t0 + tt;

    bf16x8 xa0 = cvt8(pf[0], pf[1], pf[2], pf[3]);
    bf16x8 xa1 = cvt8(pf[4], pf[5], pf[6], pf[7]);

    __syncthreads();   // previous step-2 LDS reads (or zero-init) complete

    // ---- step 1: Z[c][pv] = X[c][u] @ Ae[pv][u]^T, scattered to Zt[v][p*64+c]
    #pragma unroll
    for (int n = 0; n < 14; ++n) {
      const bf16_t* ar = Ae + (((n << 4) + l15) << 6) + (quad << 3);
      f32x4 acc = {0.f, 0.f, 0.f, 0.f};
      acc = mfma16(xa0, *(const bf16x8*)(ar), acc);
      acc = mfma16(xa1, *(const bf16x8*)(ar + 32), acc);
      uint32* dst = (uint32*)(Zt + zoff[n]);
      dst[0] = pk2(acc[0], acc[1]);
      dst[1] = pk2(acc[2], acc[3]);
    }

    // prefetch next t's x (global only — no LDS dependency, hides under barrier)
    if (tt < 3) loadx(pf, x, xrow0 + (size_t)(t + 1) * 54);

    __syncthreads();   // Zt ready

    // ---- step 2: D[v][o] = Zt[v][K] @ W2[o][K]^T ----
    const size_t obase = (((size_t)((b << 6) + oc) << 9) + (size_t)t) * 54;
    #pragma unroll
    for (int mi = 0; mi < 4; ++mi) {
      f32x4 acc = {0.f, 0.f, 0.f, 0.f};
      #pragma unroll
      for (int kk = 0; kk < 8; ++kk) {
        bf16x8 za = *(const bf16x8*)(Zt + ((mi << 4) + l15) * ZS
                                        + (kk << 5) + (quad << 3));
        acc = mfma16(za, wf[kk], acc);
      }
      const int v0 = (mi << 4) + (quad << 2);
      if (v0 + 3 < 54) {
        float y0 = acc[0] + bsv, y1 = acc[1] + bsv, y2 = acc[2] + bsv, y3 = acc[3] + bsv;
        if (YBF16) {
          uint32* d = (uint32*)((bf16_t*)yprev + obase + v0);
          d[0] = pk2(y0, y1); d[1] = pk2(y2, y3);
        } else {
          float2* d = (float2*)((float*)yprev + obase + v0);
          d[0] = make_float2(y0, y1); d[1] = make_float2(y2, y3);
        }
        ssum += y0 + y1 + y2 + y3;
        ssq  += y0 * y0 + y1 * y1 + y2 * y2 + y3 * y3;
      } else if (v0 == 52) {
        float y0 = acc[0] + bsv, y1 = acc[1] + bsv;
        if (YBF16) {
          *(uint32*)((bf16_t*)yprev + obase + v0) = pk2(y0, y1);
        } else {
          *(float2*)((float*)yprev + obase + v0) = make_float2(y0, y1);
        }
        ssum += y0 + y1;
        ssq  += y0 * y0 + y1 * y1;
      }
    }
  }

  // reduce stats across the 4 quads holding the same channel
  ssum += __shfl_xor(ssum, 16); ssq += __shfl_xor(ssq, 16);
  ssum += __shfl_xor(ssum, 32); ssq += __shfl_xor(ssq, 32);
  if (L < 16) {
    float* sb = stats + (bid & 63) * 128;
    atomicAdd(&sb[oc], ssum);
    atomicAdd(&sb[64 + oc], ssq);
  }
}

// ---------------- k_finalize ----------------
__global__ void k_finalize(const float* __restrict__ gamma, const float* __restrict__ beta,
                           const float* __restrict__ stats, float* __restrict__ ac) {
  int o = threadIdx.x;
  if (o >= 64) return;
  float S = 0.f, Q = 0.f;
  for (int buf = 0; buf < 64; ++buf) {
    S += stats[buf * 128 + o];
    Q += stats[buf * 128 + 64 + o];
  }
  const float inv = 1.0f / 884736.0f;
  float mean = S * inv;
  float var  = Q * inv - mean * mean;
  float a = gamma[o] * rsqrtf(var + 1e-5f);
  ac[o] = a;
  ac[64 + o] = beta[o] - mean * a;
}

// ---------------- k_pass2 ----------------
template<bool YBF16>
__global__ __launch_bounds__(256) void k_pass2(const float* __restrict__ x,
                                               const float* __restrict__ ac,
                                               const void* __restrict__ yprev,
                                               float* __restrict__ out) {
  const int slab = blockIdx.y;
  const int o = slab & 63;
  const size_t base = (size_t)slab * 27648 + (size_t)(((blockIdx.x << 8) + threadIdx.x) << 2);
  const float a = ac[o], c = ac[64 + o];
  float y0, y1, y2, y3;
  if (YBF16) {
    bf16x4 yp = *(const bf16x4*)((const bf16_t*)yprev + base);
    y0 = (float)yp[0]; y1 = (float)yp[1]; y2 = (float)yp[2]; y3 = (float)yp[3];
  } else {
    float4 yp = *(const float4*)((const float*)yprev + base);
    y0 = yp.x; y1 = yp.y; y2 = yp.z; y3 = yp.w;
  }
  float4 xv = *(const float4*)(x + base);
  float4 r;
  r.x = fmaxf(fmaf(a, y0, c), 0.f) + xv.x;
  r.y = fmaxf(fmaf(a, y1, c), 0.f) + xv.y;
  r.z = fmaxf(fmaf(a, y2, c), 0.f) + xv.z;
  r.w = fmaxf(fmaf(a, y3, c), 0.f) + xv.w;
  *(float4*)(out + base) = r;
}

extern "C" void kernel_launch(void* const* d_in, const int* in_sizes, int n_in,
                              void* d_out, int out_size, void* d_ws, size_t ws_size,
                              hipStream_t stream) {
  const float* x     = (const float*)d_in[0];
  const float* A     = (const float*)d_in[1];
  const float* g     = (const float*)d_in[2];
  const float* W     = (const float*)d_in[3];
  const float* bias  = (const float*)d_in[4];
  const float* gamma = (const float*)d_in[5];
  const float* beta  = (const float*)d_in[6];

  char* ws = (char*)d_ws;
  bf16_t* W2    = (bf16_t*)(ws + 0);       // 32768 B
  bf16_t* Ae    = (bf16_t*)(ws + 32768);   // 28672 B
  float*  bsum  = (float*)(ws + 61440);    // 256 B
  float*  stats = (float*)(ws + 61696);    // 32768 B
  float*  ac    = (float*)(ws + 94464);    // 512 B
  const size_t YP_OFF   = 98304;
  const size_t YP_BYTES = (size_t)32 * 64 * 512 * 54 * 2;   // 113246208
  float* out = (float*)d_out;

  k_prep<<<64, 256, 0, stream>>>(A, g, W, bias, W2, Ae, bsum, stats);

  if (ws_size >= YP_OFF + YP_BYTES + 4096) {
    bf16_t* ypre = (bf16_t*)(ws + YP_OFF);
    k_pass1<true><<<4096, 256, 0, stream>>>(x, W2, Ae, bsum, ypre, stats);
    k_finalize<<<1, 64, 0, stream>>>(gamma, beta, stats, ac);
    k_pass2<true><<<dim3(27, 2048), 256, 0, stream>>>(x, ac, ypre, out);
  } else {
    // fallback: fp32 ypre staged in d_out, pass2 normalizes in place
    k_pass1<false><<<4096, 256, 0, stream>>>(x, W2, Ae, bsum, out, stats);
    k_finalize<<<1, 64, 0, stream>>>(gamma, beta, stats, ac);
    k_pass2<false><<<dim3(27, 2048), 256, 0, stream>>>(x, ac, out, out);
  }
}

// Round 2
// 757.765 us; speedup vs baseline: 1.0138x; 1.0138x over previous
//
#include <hip/hip_runtime.h>
#include <hip/hip_bf16.h>

// GraphConvNormRelu: y = einsum('bctu,puv,poc->botv', x, A*g, W) + sum_p b;
// train-mode BN over (B,T,V); relu; +x residual.  B=32, C=64, T=512, V=54, P=4.
//
// R4 structure (u-first contraction + coalesced LDS staging):
//   k_prep  : bf16 W2 [o][p*64+c], bf16 Ae [pv=p*56+v][u(64)] zero-padded,
//             bias sums, zero stat buffers.
//   k_pass1 : per block (b, 4 t):
//             stage  : x[c][t][u] tile -> Xs[64][72] bf16 via lane-contiguous
//                      float2 global loads (full 64B-line utilization; R3's
//                      8B-scattered frag loads caused 3.6x L2-miss overfetch).
//                      Next-t loads issued early (latency hides under MFMA).
//             step 1 : Z[c][pv] = X[c][u] @ Ae[pv][u]^T, A-frags from Xs,
//                      scatter Z -> Zt[v][p*64+c] in LDS.
//             step 2 : D[v][o] = Zt[v][K=256] @ W2[o][K]^T, W2 frags
//                      persistent in registers. Stores + bucketed stats.
//             LDS 43 KB (Zt 33.8 + Xs 9.2) -> 3 blocks/CU; 2 barriers per t.
//   k_finalize, k_pass2 (unchanged).

typedef __bf16 bf16_t;
typedef __bf16 bf16x8 __attribute__((ext_vector_type(8)));
typedef __bf16 bf16x4 __attribute__((ext_vector_type(4)));
typedef float  f32x4  __attribute__((ext_vector_type(4)));
typedef unsigned int uint32;

static __device__ __forceinline__ f32x4 mfma16(bf16x8 a, bf16x8 b, f32x4 c) {
  return __builtin_amdgcn_mfma_f32_16x16x32_bf16(a, b, c, 0, 0, 0);
}
static __device__ __forceinline__ uint32 pk2(float a, float b) {
  union { __bf16 h; unsigned short u; } ua, ub;
  ua.h = (__bf16)a; ub.h = (__bf16)b;
  return (uint32)ua.u | ((uint32)ub.u << 16);
}

#define XTOT 56623104ull   // 32*64*512*54 floats

// ---------------- k_prep ----------------
__global__ __launch_bounds__(256) void k_prep(
    const float* __restrict__ A, const float* __restrict__ g,
    const float* __restrict__ W, const float* __restrict__ bias,
    bf16_t* __restrict__ W2, bf16_t* __restrict__ Ae,
    float* __restrict__ bsum, float* __restrict__ stats) {
  int i = blockIdx.x * 256 + threadIdx.x;
  if (i < 16384) {                       // W2[o][p*64+c] = W[p][o][c]
    int o = i >> 8, k = i & 255, p = k >> 6, c = k & 63;
    W2[i] = (bf16_t)W[p * 4096 + o * 64 + c];
  }
  if (i < 224 * 64) {                    // Ae[p*56+v][u] = A[p][u][v]*g[p][u][v]
    int pv = i >> 6, u = i & 63;
    int p = pv / 56, v = pv - p * 56;
    float val = 0.f;
    if (v < 54 && u < 54) {
      int idx = (p * 54 + u) * 54 + v;
      val = A[idx] * g[idx];
    }
    Ae[i] = (bf16_t)val;
  }
  if (i < 64) {
    float s = 0.f;
    for (int p = 0; p < 4; ++p) s += bias[p * 64 + i];
    bsum[i] = s;
  }
  if (i < 8192) stats[i] = 0.f;
}

// ---------------- k_pass1 ----------------
#define ZS  264   // Zt row stride bf16: 132 dwords, gcd(132,32)=4 -> <=2-way banks
#define XSS 72    // Xs row stride bf16: 36 dwords == 4 mod 32 -> staggered banks

template<bool YBF16>
__global__ __launch_bounds__(256, 3) void k_pass1(
    const float* __restrict__ x, const bf16_t* __restrict__ W2,
    const bf16_t* __restrict__ Ae, const float* __restrict__ bsum,
    void* __restrict__ yprev, float* __restrict__ stats) {
  __shared__ bf16_t Zt[64 * ZS];    // 33792 B
  __shared__ bf16_t Xs[64 * XSS];   //  9216 B  (43008 total -> 3 blocks/CU)

  const int tid  = threadIdx.x;
  const int bid  = blockIdx.x;
  const int b    = bid >> 7;
  const int t0   = (bid & 127) << 2;
  const int w    = tid >> 6;
  const int L    = tid & 63;
  const int quad = L >> 4;
  const int l15  = L & 15;

  // zero Zt pad rows 56..63 once (step-2 A-frag pad rows; rows 54/55 get
  // written zeros every t via the zero Ae columns)
  for (int i = tid; i < 8 * ZS / 2; i += 256)
    ((uint32*)(Zt + 56 * ZS))[i] = 0u;

  // persistent step-2 B-frags: W2 row o = w*16+l15, k = kk*32+quad*8
  bf16x8 wf[8];
  #pragma unroll
  for (int kk = 0; kk < 8; ++kk)
    wf[kk] = *(const bf16x8*)(W2 + (((w << 4) + l15) << 8) + (kk << 5) + (quad << 3));

  // step-1 scatter offsets: col pv = n*16+l15 -> Zt[v][p*64 + c0]
  int zoff[14];
  #pragma unroll
  for (int n = 0; n < 14; ++n) {
    int pv = (n << 4) + l15;
    int p = pv / 56;
    int v = pv - p * 56;
    zoff[n] = v * ZS + (p << 6) + (w << 4) + (quad << 2);
  }

  const int oc  = (w << 4) + l15;      // step-2 output channel; step-1 c-row
  const float bsv = bsum[oc];
  float ssum = 0.f, ssq = 0.f;

  // ---- staging geometry: thread covers (c = (tid>>5) + 8j, f2 = tid&31) ----
  // global: consecutive lanes read consecutive float2 within a c-row (coalesced)
  const size_t LIM   = XTOT - 2;
  const size_t gbase = ((size_t)(b << 6) + (tid >> 5)) * 27648 + ((size_t)(tid & 31) << 1);
  uint32* xsd = (uint32*)((char*)Xs + (tid >> 5) * (XSS * 2) + ((tid & 31) << 2));

  float2 pf[8];
  #pragma unroll
  for (int j = 0; j < 8; ++j) {
    size_t a = gbase + (size_t)j * 221184 + (size_t)t0 * 54;
    if (a > LIM) a = LIM;               // only the global last row can overrun;
    pf[j] = *(const float2*)(x + a);    // u>=54 lands in Ae zero columns
  }

  for (int tt = 0; tt < 4; ++tt) {
    const int t = t0 + tt;

    // write staged tile (bf16 pairs, bank-staggered)
    #pragma unroll
    for (int j = 0; j < 8; ++j) xsd[j * 288] = pk2(pf[j].x, pf[j].y);

    // issue next t's global loads (consumed at next iteration's ds_writes;
    // latency hides under step-1 + step-2)
    if (tt < 3) {
      #pragma unroll
      for (int j = 0; j < 8; ++j) {
        size_t a = gbase + (size_t)j * 221184 + (size_t)(t + 1) * 54;
        if (a > LIM) a = LIM;
        pf[j] = *(const float2*)(x + a);
      }
    }

    __syncthreads();   // Xs ready; prev step-2 Zt reads complete

    // ---- step 1: Z[c][pv] = X[c][u] @ Ae[pv][u]^T ----
    const bf16_t* xr = Xs + oc * XSS;
    bf16x8 xa0 = *(const bf16x8*)(xr + (quad << 3));
    bf16x8 xa1 = *(const bf16x8*)(xr + 32 + (quad << 3));
    #pragma unroll
    for (int n = 0; n < 14; ++n) {
      const bf16_t* ar = Ae + (((n << 4) + l15) << 6) + (quad << 3);
      f32x4 acc = {0.f, 0.f, 0.f, 0.f};
      acc = mfma16(xa0, *(const bf16x8*)(ar), acc);
      acc = mfma16(xa1, *(const bf16x8*)(ar + 32), acc);
      uint32* dst = (uint32*)(Zt + zoff[n]);
      dst[0] = pk2(acc[0], acc[1]);
      dst[1] = pk2(acc[2], acc[3]);
    }

    __syncthreads();   // Zt ready

    // ---- step 2: D[v][o] = Zt[v][K] @ W2[o][K]^T ----
    const size_t obase = (((size_t)((b << 6) + oc) << 9) + (size_t)t) * 54;
    #pragma unroll
    for (int mi = 0; mi < 4; ++mi) {
      f32x4 acc = {0.f, 0.f, 0.f, 0.f};
      #pragma unroll
      for (int kk = 0; kk < 8; ++kk) {
        bf16x8 za = *(const bf16x8*)(Zt + ((mi << 4) + l15) * ZS
                                        + (kk << 5) + (quad << 3));
        acc = mfma16(za, wf[kk], acc);
      }
      const int v0 = (mi << 4) + (quad << 2);
      if (v0 + 3 < 54) {
        float y0 = acc[0] + bsv, y1 = acc[1] + bsv, y2 = acc[2] + bsv, y3 = acc[3] + bsv;
        if (YBF16) {
          uint32* d = (uint32*)((bf16_t*)yprev + obase + v0);
          d[0] = pk2(y0, y1); d[1] = pk2(y2, y3);
        } else {
          float2* d = (float2*)((float*)yprev + obase + v0);
          d[0] = make_float2(y0, y1); d[1] = make_float2(y2, y3);
        }
        ssum += y0 + y1 + y2 + y3;
        ssq  += y0 * y0 + y1 * y1 + y2 * y2 + y3 * y3;
      } else if (v0 == 52) {
        float y0 = acc[0] + bsv, y1 = acc[1] + bsv;
        if (YBF16) {
          *(uint32*)((bf16_t*)yprev + obase + v0) = pk2(y0, y1);
        } else {
          *(float2*)((float*)yprev + obase + v0) = make_float2(y0, y1);
        }
        ssum += y0 + y1;
        ssq  += y0 * y0 + y1 * y1;
      }
    }
  }

  // reduce stats across the 4 quads holding the same channel
  ssum += __shfl_xor(ssum, 16); ssq += __shfl_xor(ssq, 16);
  ssum += __shfl_xor(ssum, 32); ssq += __shfl_xor(ssq, 32);
  if (L < 16) {
    float* sb = stats + (bid & 63) * 128;
    atomicAdd(&sb[oc], ssum);
    atomicAdd(&sb[64 + oc], ssq);
  }
}

// ---------------- k_finalize ----------------
__global__ void k_finalize(const float* __restrict__ gamma, const float* __restrict__ beta,
                           const float* __restrict__ stats, float* __restrict__ ac) {
  int o = threadIdx.x;
  if (o >= 64) return;
  float S = 0.f, Q = 0.f;
  for (int buf = 0; buf < 64; ++buf) {
    S += stats[buf * 128 + o];
    Q += stats[buf * 128 + 64 + o];
  }
  const float inv = 1.0f / 884736.0f;
  float mean = S * inv;
  float var  = Q * inv - mean * mean;
  float a = gamma[o] * rsqrtf(var + 1e-5f);
  ac[o] = a;
  ac[64 + o] = beta[o] - mean * a;
}

// ---------------- k_pass2 ----------------
template<bool YBF16>
__global__ __launch_bounds__(256) void k_pass2(const float* __restrict__ x,
                                               const float* __restrict__ ac,
                                               const void* __restrict__ yprev,
                                               float* __restrict__ out) {
  const int slab = blockIdx.y;
  const int o = slab & 63;
  const size_t base = (size_t)slab * 27648 + (size_t)(((blockIdx.x << 8) + threadIdx.x) << 2);
  const float a = ac[o], c = ac[64 + o];
  float y0, y1, y2, y3;
  if (YBF16) {
    bf16x4 yp = *(const bf16x4*)((const bf16_t*)yprev + base);
    y0 = (float)yp[0]; y1 = (float)yp[1]; y2 = (float)yp[2]; y3 = (float)yp[3];
  } else {
    float4 yp = *(const float4*)((const float*)yprev + base);
    y0 = yp.x; y1 = yp.y; y2 = yp.z; y3 = yp.w;
  }
  float4 xv = *(const float4*)(x + base);
  float4 r;
  r.x = fmaxf(fmaf(a, y0, c), 0.f) + xv.x;
  r.y = fmaxf(fmaf(a, y1, c), 0.f) + xv.y;
  r.z = fmaxf(fmaf(a, y2, c), 0.f) + xv.z;
  r.w = fmaxf(fmaf(a, y3, c), 0.f) + xv.w;
  *(float4*)(out + base) = r;
}

extern "C" void kernel_launch(void* const* d_in, const int* in_sizes, int n_in,
                              void* d_out, int out_size, void* d_ws, size_t ws_size,
                              hipStream_t stream) {
  const float* x     = (const float*)d_in[0];
  const float* A     = (const float*)d_in[1];
  const float* g     = (const float*)d_in[2];
  const float* W     = (const float*)d_in[3];
  const float* bias  = (const float*)d_in[4];
  const float* gamma = (const float*)d_in[5];
  const float* beta  = (const float*)d_in[6];

  char* ws = (char*)d_ws;
  bf16_t* W2    = (bf16_t*)(ws + 0);       // 32768 B
  bf16_t* Ae    = (bf16_t*)(ws + 32768);   // 28672 B
  float*  bsum  = (float*)(ws + 61440);    // 256 B
  float*  stats = (float*)(ws + 61696);    // 32768 B
  float*  ac    = (float*)(ws + 94464);    // 512 B
  const size_t YP_OFF   = 98304;
  const size_t YP_BYTES = (size_t)32 * 64 * 512 * 54 * 2;   // 113246208
  float* out = (float*)d_out;

  k_prep<<<64, 256, 0, stream>>>(A, g, W, bias, W2, Ae, bsum, stats);

  if (ws_size >= YP_OFF + YP_BYTES + 4096) {
    bf16_t* ypre = (bf16_t*)(ws + YP_OFF);
    k_pass1<true><<<4096, 256, 0, stream>>>(x, W2, Ae, bsum, ypre, stats);
    k_finalize<<<1, 64, 0, stream>>>(gamma, beta, stats, ac);
    k_pass2<true><<<dim3(27, 2048), 256, 0, stream>>>(x, ac, ypre, out);
  } else {
    // fallback: fp32 ypre staged in d_out, pass2 normalizes in place
    k_pass1<false><<<4096, 256, 0, stream>>>(x, W2, Ae, bsum, out, stats);
    k_finalize<<<1, 64, 0, stream>>>(gamma, beta, stats, ac);
    k_pass2<false><<<dim3(27, 2048), 256, 0, stream>>>(x, ac, out, out);
  }
}

// Round 3
// 729.054 us; speedup vs baseline: 1.0538x; 1.0394x over previous
//
#include <hip/hip_runtime.h>
#include <hip/hip_bf16.h>

// GraphConvNormRelu: y = einsum('bctu,puv,poc->botv', x, A*g, W) + sum_p b;
// train-mode BN over (B,T,V); relu; +x residual.  B=32, C=64, T=512, V=54, P=4.
//
// R5 structure (R4 + block-contiguous ypre layout):
//   k_pass1 : per block (b, 4 t):
//             stage  : x tile -> Xs[64][72] bf16 via lane-contiguous float2
//                      loads; next-t loads prefetched.
//             step 1 : Z[c][pv] = X[c][u] @ Ae[pv][u]^T -> Zt[v][p*64+c] LDS.
//             step 2 : D[v][o] = Zt[v][256] @ W2[o][256]^T.
//             ypre written as yblk[bid][tt][oc][v]: each tt phase emits one
//             dense 128B-aligned 6912B slice, fully dirtied within one
//             step-2 burst -> no partial-line eviction RMW (R4: WRITE was
//             4.8x ypre size with the scattered [b][o][t][v] layout).
//   k_pass2 : slab-major (perfect x/out fp32 streams); ypre gathered via
//             magic-div index permutation (contiguous 108B runs per row).
//   k_prep, k_finalize unchanged.

typedef __bf16 bf16_t;
typedef __bf16 bf16x8 __attribute__((ext_vector_type(8)));
typedef __bf16 bf16x4 __attribute__((ext_vector_type(4)));
typedef float  f32x4  __attribute__((ext_vector_type(4)));
typedef unsigned int uint32;

static __device__ __forceinline__ f32x4 mfma16(bf16x8 a, bf16x8 b, f32x4 c) {
  return __builtin_amdgcn_mfma_f32_16x16x32_bf16(a, b, c, 0, 0, 0);
}
static __device__ __forceinline__ uint32 pk2(float a, float b) {
  union { __bf16 h; unsigned short u; } ua, ub;
  ua.h = (__bf16)a; ub.h = (__bf16)b;
  return (uint32)ua.u | ((uint32)ub.u << 16);
}

#define XTOT 56623104ull   // 32*64*512*54 floats

// ---------------- k_prep ----------------
__global__ __launch_bounds__(256) void k_prep(
    const float* __restrict__ A, const float* __restrict__ g,
    const float* __restrict__ W, const float* __restrict__ bias,
    bf16_t* __restrict__ W2, bf16_t* __restrict__ Ae,
    float* __restrict__ bsum, float* __restrict__ stats) {
  int i = blockIdx.x * 256 + threadIdx.x;
  if (i < 16384) {                       // W2[o][p*64+c] = W[p][o][c]
    int o = i >> 8, k = i & 255, p = k >> 6, c = k & 63;
    W2[i] = (bf16_t)W[p * 4096 + o * 64 + c];
  }
  if (i < 224 * 64) {                    // Ae[p*56+v][u] = A[p][u][v]*g[p][u][v]
    int pv = i >> 6, u = i & 63;
    int p = pv / 56, v = pv - p * 56;
    float val = 0.f;
    if (v < 54 && u < 54) {
      int idx = (p * 54 + u) * 54 + v;
      val = A[idx] * g[idx];
    }
    Ae[i] = (bf16_t)val;
  }
  if (i < 64) {
    float s = 0.f;
    for (int p = 0; p < 4; ++p) s += bias[p * 64 + i];
    bsum[i] = s;
  }
  if (i < 8192) stats[i] = 0.f;
}

// ---------------- k_pass1 ----------------
#define ZS  264   // Zt row stride bf16: 132 dwords, gcd(132,32)=4 -> <=2-way banks
#define XSS 72    // Xs row stride bf16: 36 dwords == 4 mod 32 -> staggered banks

template<bool YBF16>
__global__ __launch_bounds__(256, 3) void k_pass1(
    const float* __restrict__ x, const bf16_t* __restrict__ W2,
    const bf16_t* __restrict__ Ae, const float* __restrict__ bsum,
    void* __restrict__ yprev, float* __restrict__ stats) {
  __shared__ bf16_t Zt[64 * ZS];    // 33792 B
  __shared__ bf16_t Xs[64 * XSS];   //  9216 B  (43008 total -> 3 blocks/CU)

  const int tid  = threadIdx.x;
  const int bid  = blockIdx.x;
  const int b    = bid >> 7;
  const int t0   = (bid & 127) << 2;
  const int w    = tid >> 6;
  const int L    = tid & 63;
  const int quad = L >> 4;
  const int l15  = L & 15;

  // zero Zt pad rows 56..63 once (step-2 A-frag pad rows; rows 54/55 get
  // written zeros every t via the zero Ae columns)
  for (int i = tid; i < 8 * ZS / 2; i += 256)
    ((uint32*)(Zt + 56 * ZS))[i] = 0u;

  // persistent step-2 B-frags: W2 row o = w*16+l15, k = kk*32+quad*8
  bf16x8 wf[8];
  #pragma unroll
  for (int kk = 0; kk < 8; ++kk)
    wf[kk] = *(const bf16x8*)(W2 + (((w << 4) + l15) << 8) + (kk << 5) + (quad << 3));

  // step-1 scatter offsets: col pv = n*16+l15 -> Zt[v][p*64 + c0]
  int zoff[14];
  #pragma unroll
  for (int n = 0; n < 14; ++n) {
    int pv = (n << 4) + l15;
    int p = pv / 56;
    int v = pv - p * 56;
    zoff[n] = v * ZS + (p << 6) + (w << 4) + (quad << 2);
  }

  const int oc  = (w << 4) + l15;      // step-2 output channel; step-1 c-row
  const float bsv = bsum[oc];
  float ssum = 0.f, ssq = 0.f;

  // ---- staging geometry: thread covers (c = (tid>>5) + 8j, f2 = tid&31) ----
  const size_t LIM   = XTOT - 2;
  const size_t gbase = ((size_t)(b << 6) + (tid >> 5)) * 27648 + ((size_t)(tid & 31) << 1);
  uint32* xsd = (uint32*)((char*)Xs + (tid >> 5) * (XSS * 2) + ((tid & 31) << 2));

  float2 pf[8];
  #pragma unroll
  for (int j = 0; j < 8; ++j) {
    size_t a = gbase + (size_t)j * 221184 + (size_t)t0 * 54;
    if (a > LIM) a = LIM;               // only the global last row can overrun;
    pf[j] = *(const float2*)(x + a);    // u>=54 lands in Ae zero columns
  }

  for (int tt = 0; tt < 4; ++tt) {
    const int t = t0 + tt;

    // write staged tile (bf16 pairs, bank-staggered)
    #pragma unroll
    for (int j = 0; j < 8; ++j) xsd[j * 288] = pk2(pf[j].x, pf[j].y);

    // issue next t's global loads (latency hides under step-1 + step-2)
    if (tt < 3) {
      #pragma unroll
      for (int j = 0; j < 8; ++j) {
        size_t a = gbase + (size_t)j * 221184 + (size_t)(t + 1) * 54;
        if (a > LIM) a = LIM;
        pf[j] = *(const float2*)(x + a);
      }
    }

    __syncthreads();   // Xs ready; prev step-2 Zt reads complete

    // ---- step 1: Z[c][pv] = X[c][u] @ Ae[pv][u]^T ----
    const bf16_t* xr = Xs + oc * XSS;
    bf16x8 xa0 = *(const bf16x8*)(xr + (quad << 3));
    bf16x8 xa1 = *(const bf16x8*)(xr + 32 + (quad << 3));
    #pragma unroll
    for (int n = 0; n < 14; ++n) {
      const bf16_t* ar = Ae + (((n << 4) + l15) << 6) + (quad << 3);
      f32x4 acc = {0.f, 0.f, 0.f, 0.f};
      acc = mfma16(xa0, *(const bf16x8*)(ar), acc);
      acc = mfma16(xa1, *(const bf16x8*)(ar + 32), acc);
      uint32* dst = (uint32*)(Zt + zoff[n]);
      dst[0] = pk2(acc[0], acc[1]);
      dst[1] = pk2(acc[2], acc[3]);
    }

    __syncthreads();   // Zt ready

    // ---- step 2: D[v][o] = Zt[v][K] @ W2[o][K]^T ----
    // YBF16: block-contiguous yblk[bid][tt][oc][v]; slice 6912B = 54*128,
    //        128B-aligned, fully written within this step-2 burst.
    // else : legacy [b][o][t][v] fp32 (in-place-safe for the fallback pass2).
    const size_t ybase  = (size_t)bid * 13824 + (size_t)tt * 3456 + (size_t)oc * 54;
    const size_t obase  = (((size_t)((b << 6) + oc) << 9) + (size_t)t) * 54;
    #pragma unroll
    for (int mi = 0; mi < 4; ++mi) {
      f32x4 acc = {0.f, 0.f, 0.f, 0.f};
      #pragma unroll
      for (int kk = 0; kk < 8; ++kk) {
        bf16x8 za = *(const bf16x8*)(Zt + ((mi << 4) + l15) * ZS
                                        + (kk << 5) + (quad << 3));
        acc = mfma16(za, wf[kk], acc);
      }
      const int v0 = (mi << 4) + (quad << 2);
      if (v0 + 3 < 54) {
        float y0 = acc[0] + bsv, y1 = acc[1] + bsv, y2 = acc[2] + bsv, y3 = acc[3] + bsv;
        if (YBF16) {
          uint32* d = (uint32*)((bf16_t*)yprev + ybase + v0);
          d[0] = pk2(y0, y1); d[1] = pk2(y2, y3);
        } else {
          float2* d = (float2*)((float*)yprev + obase + v0);
          d[0] = make_float2(y0, y1); d[1] = make_float2(y2, y3);
        }
        ssum += y0 + y1 + y2 + y3;
        ssq  += y0 * y0 + y1 * y1 + y2 * y2 + y3 * y3;
      } else if (v0 == 52) {
        float y0 = acc[0] + bsv, y1 = acc[1] + bsv;
        if (YBF16) {
          *(uint32*)((bf16_t*)yprev + ybase + v0) = pk2(y0, y1);
        } else {
          *(float2*)((float*)yprev + obase + v0) = make_float2(y0, y1);
        }
        ssum += y0 + y1;
        ssq  += y0 * y0 + y1 * y1;
      }
    }
  }

  // reduce stats across the 4 quads holding the same channel
  ssum += __shfl_xor(ssum, 16); ssq += __shfl_xor(ssq, 16);
  ssum += __shfl_xor(ssum, 32); ssq += __shfl_xor(ssq, 32);
  if (L < 16) {
    float* sb = stats + (bid & 63) * 128;
    atomicAdd(&sb[oc], ssum);
    atomicAdd(&sb[64 + oc], ssq);
  }
}

// ---------------- k_finalize ----------------
__global__ void k_finalize(const float* __restrict__ gamma, const float* __restrict__ beta,
                           const float* __restrict__ stats, float* __restrict__ ac) {
  int o = threadIdx.x;
  if (o >= 64) return;
  float S = 0.f, Q = 0.f;
  for (int buf = 0; buf < 64; ++buf) {
    S += stats[buf * 128 + o];
    Q += stats[buf * 128 + 64 + o];
  }
  const float inv = 1.0f / 884736.0f;
  float mean = S * inv;
  float var  = Q * inv - mean * mean;
  float a = gamma[o] * rsqrtf(var + 1e-5f);
  ac[o] = a;
  ac[64 + o] = beta[o] - mean * a;
}

// ---------------- k_pass2 ----------------
template<bool YBF16>
__global__ __launch_bounds__(256) void k_pass2(const float* __restrict__ x,
                                               const float* __restrict__ ac,
                                               const void* __restrict__ yprev,
                                               float* __restrict__ out) {
  const int slab = blockIdx.y;
  const int o = slab & 63;
  const int i0 = ((blockIdx.x << 8) + threadIdx.x) << 2;
  const size_t base = (size_t)slab * 27648 + (size_t)i0;
  const float a = ac[o], c = ac[64 + o];
  float y0, y1, y2, y3;
  if (YBF16) {
    // yblk[bid][tt][oc][v] gather: idx -> (t = idx/54, v = idx%54)
    const int b = slab >> 6;
    const bf16_t* yp = (const bf16_t*)yprev;
    float ye[4];
    #pragma unroll
    for (int e = 0; e < 4; ++e) {
      unsigned idx = (unsigned)(i0 + e);
      unsigned t = (idx * 38837u) >> 21;        // floor(idx/54), idx < 27648
      unsigned v = idx - t * 54u;
      size_t yi = ((size_t)(b * 128 + (t >> 2))) * 13824
                + (size_t)(t & 3) * 3456 + (size_t)o * 54 + v;
      ye[e] = (float)yp[yi];
    }
    y0 = ye[0]; y1 = ye[1]; y2 = ye[2]; y3 = ye[3];
  } else {
    float4 yp = *(const float4*)((const float*)yprev + base);
    y0 = yp.x; y1 = yp.y; y2 = yp.z; y3 = yp.w;
  }
  float4 xv = *(const float4*)(x + base);
  float4 r;
  r.x = fmaxf(fmaf(a, y0, c), 0.f) + xv.x;
  r.y = fmaxf(fmaf(a, y1, c), 0.f) + xv.y;
  r.z = fmaxf(fmaf(a, y2, c), 0.f) + xv.z;
  r.w = fmaxf(fmaf(a, y3, c), 0.f) + xv.w;
  *(float4*)(out + base) = r;
}

extern "C" void kernel_launch(void* const* d_in, const int* in_sizes, int n_in,
                              void* d_out, int out_size, void* d_ws, size_t ws_size,
                              hipStream_t stream) {
  const float* x     = (const float*)d_in[0];
  const float* A     = (const float*)d_in[1];
  const float* g     = (const float*)d_in[2];
  const float* W     = (const float*)d_in[3];
  const float* bias  = (const float*)d_in[4];
  const float* gamma = (const float*)d_in[5];
  const float* beta  = (const float*)d_in[6];

  char* ws = (char*)d_ws;
  bf16_t* W2    = (bf16_t*)(ws + 0);       // 32768 B
  bf16_t* Ae    = (bf16_t*)(ws + 32768);   // 28672 B
  float*  bsum  = (float*)(ws + 61440);    // 256 B
  float*  stats = (float*)(ws + 61696);    // 32768 B
  float*  ac    = (float*)(ws + 94464);    // 512 B
  const size_t YP_OFF   = 98304;
  const size_t YP_BYTES = (size_t)32 * 64 * 512 * 54 * 2;   // 113246208
  float* out = (float*)d_out;

  k_prep<<<64, 256, 0, stream>>>(A, g, W, bias, W2, Ae, bsum, stats);

  if (ws_size >= YP_OFF + YP_BYTES + 4096) {
    bf16_t* ypre = (bf16_t*)(ws + YP_OFF);
    k_pass1<true><<<4096, 256, 0, stream>>>(x, W2, Ae, bsum, ypre, stats);
    k_finalize<<<1, 64, 0, stream>>>(gamma, beta, stats, ac);
    k_pass2<true><<<dim3(27, 2048), 256, 0, stream>>>(x, ac, ypre, out);
  } else {
    // fallback: fp32 ypre staged in d_out (legacy layout), pass2 in place
    k_pass1<false><<<4096, 256, 0, stream>>>(x, W2, Ae, bsum, out, stats);
    k_finalize<<<1, 64, 0, stream>>>(gamma, beta, stats, ac);
    k_pass2<false><<<dim3(27, 2048), 256, 0, stream>>>(x, ac, out, out);
  }
}